// Round 10
// baseline (913.864 us; speedup 1.0000x reference)
//
#include <hip/hip_runtime.h>

// ---------------- problem constants ----------------
#define N_WORDS 16384
#define MAXL    16
#define VOCABSZ 128
#define EMBD    64
#define HID     256
#define GATES   1024        // 4*HID
#define KTOT    320         // HID + EMBD (x folded into K)
#define AROW    328         // A row stride in shorts (656 B = 640 + 16 pad)
#define M_TILE  64          // words per workgroup
#define NT      256         // word tiles (N_WORDS / M_TILE)

typedef __attribute__((ext_vector_type(8))) short bf16x8;  // 8 bf16 = 4 VGPRs
typedef __attribute__((ext_vector_type(4))) float f32x4;
typedef __attribute__((ext_vector_type(4))) int   i32x4;

// ---------------- workspace layout (bytes) ----------------
// wsw : swizzled weights, A-fragment order: [dir][R 0..63][kk 0..9][lane 0..63][8 bf16]
//       row-tile R covers units 4R..4R+3, rows m = 4*uu + gate_type (unit-major interleave)
#define OFF_WSW   0ul          // 2*64*10*64*16 = 1310720
#define OFF_EMB   1310720ul    // 128*64 bf16 = 16384
#define OFF_BIAS  1327104ul    // 2*1024 f32 = 8192 (interleaved unit-major: [4*unit+type])
#define OFF_SORT  1335296ul    // 16384 ints = 65536
#define OFF_HIST  1400832ul    // 16 ints
#define OFF_BASE  1400896ul    // 16 ints
#define OFF_CNT   1400960ul    // 16 ints
#define OFF_C     1401088ul    // 512 blocks * 64 KB = 33554432  (coalesced fp32 cell state)

__device__ inline short tobf(float f) {           // fp32 -> bf16 RNE
  unsigned u = __float_as_uint(f);
  unsigned r = (u + 0x7fffu + ((u >> 16) & 1u)) >> 16;
  return (short)r;
}
// raw transcendental units via inline asm (assembles per cdna4_isa.md §3)
__device__ inline float aexp2(float x) { float r; asm("v_exp_f32 %0, %1" : "=v"(r) : "v"(x)); return r; }
__device__ inline float arcp(float x)  { float r; asm("v_rcp_f32 %0, %1" : "=v"(r) : "v"(x)); return r; }
__device__ inline float fsig(float x)   { return arcp(1.0f + aexp2(x * -1.4426950408889634f)); }
__device__ inline float ftanhf(float x) { return 1.0f - 2.0f * arcp(1.0f + aexp2(x * 2.8853900817779268f)); }

// ---------------- prep: weight swizzle into MFMA *A*-fragment layout ----------------
// A[m][k] for 16x16x32: m = lane&15, k = kk*32 + (lane>>4)*8 + j
// row m of row-tile R: unit = 4R + (m>>2), gate type = m&3, gate row g = type*256 + unit
__global__ void prep_w(const float* __restrict__ Wihf, const float* __restrict__ Whhf,
                       const float* __restrict__ Wihb, const float* __restrict__ Whhb,
                       short* __restrict__ wsw) {
  int id = blockIdx.x * 256 + threadIdx.x;       // 2*64*10*64 = 81920
  if (id >= 81920) return;
  int d    = id / 40960;
  int r    = id % 40960;
  int R    = r / 640;
  int r2   = r % 640;
  int kk   = r2 / 64;
  int lane = r2 % 64;
  int m    = lane & 15;
  int unit = R * 4 + (m >> 2);
  int ty   = m & 3;
  int g    = ty * 256 + unit;
  int kb   = kk * 32 + (lane >> 4) * 8;
  const float* Wih = d ? Wihb : Wihf;
  const float* Whh = d ? Whhb : Whhf;
  bf16x8 v;
#pragma unroll
  for (int j = 0; j < 8; ++j) {
    int k = kb + j;
    float f = (k < HID) ? Whh[g * HID + k] : Wih[g * EMBD + (k - HID)];
    v[j] = tobf(f);
  }
  ((bf16x8*)wsw)[id] = v;
}

// emb -> bf16, biases -> interleaved sum ([4*unit+type], matches C-row interleave)
__global__ void prep_misc(const float* __restrict__ emb,
                          const float* __restrict__ bihf, const float* __restrict__ bhhf,
                          const float* __restrict__ bihb, const float* __restrict__ bhhb,
                          short* __restrict__ embw, float* __restrict__ biasg) {
  int id = blockIdx.x * 256 + threadIdx.x;       // 8192 + 2048 = 10240
  if (id < VOCABSZ * EMBD) {
    embw[id] = tobf(emb[id]);
  } else {
    int r = id - VOCABSZ * EMBD;
    if (r < 2048) {
      int d = r >> 10, n = r & 1023;
      int g = (n & 3) * 256 + (n >> 2);
      biasg[r] = d ? (bihb[g] + bhhb[g]) : (bihf[g] + bhhf[g]);
    }
  }
}

// ---------------- length bucketing ----------------
__global__ void k_hist(const int* __restrict__ lengths, int* __restrict__ hist) {
  int id = blockIdx.x * 256 + threadIdx.x;
  if (id < N_WORDS) atomicAdd(&hist[lengths[id] - 1], 1);
}
__global__ void k_scan(const int* __restrict__ hist, int* __restrict__ basep) {
  if (threadIdx.x == 0 && blockIdx.x == 0) {
    int s = 0;
    for (int i = 0; i < 16; ++i) { basep[i] = s; s += hist[i]; }
  }
}
__global__ void k_scat(const int* __restrict__ lengths, const int* __restrict__ basep,
                       int* __restrict__ cnt, int* __restrict__ sorted) {
  int id = blockIdx.x * 256 + threadIdx.x;
  if (id < N_WORDS) {
    int b = lengths[id] - 1;
    int p = basep[b] + atomicAdd(&cnt[b], 1);
    sorted[p] = id;
  }
}

// ---------------- main fused BiLSTM kernel ----------------
// R10 wave split: wave = (wu, wc2) = (wv>>1, wv&1).
//   wave owns units [128*wu, 128*wu+128) = rt [32*wu .. 32*wu+32)
//         and words [32*wc2, 32*wc2+32) = ct {2*wc2, 2*wc2+1}
// -> hx only 2 ct x 10 kk = 80 regs, single wc buffer 40 regs
// -> fits __launch_bounds__(256,3): 3 blocks/CU (LDS 3x50.7=152<=160)
// -> the two wc2 waves of each wu stream IDENTICAL weight addresses in
//    near-lockstep -> L1 dedup -> effective single weight stream per block.
// Latency hiding: 3 waves/SIMD interleave (no ping-pong needed) + cross-block.
// Race safety: hx snapshot (all waves) -> barrier -> disjoint h/c/out writes
// per wave -> gather_x (x region disjoint from h) -> barrier.  2 barriers/t.
__global__ __launch_bounds__(256, 3) void lstm_main(
    const int* __restrict__ char_ids, const int* __restrict__ lengths,
    const short* __restrict__ wsw, const short* __restrict__ embw,
    const float* __restrict__ biasg, const int* __restrict__ sorted,
    float* __restrict__ cws, float* __restrict__ out) {
  __shared__ __align__(16) short A[M_TILE * AROW];   // [word][ h(256) | x(64) | pad(8) ] bf16
  __shared__ __align__(16) int   charl[M_TILE * 16];
  __shared__ __align__(16) float biasl[GATES];
  __shared__ int lenl[M_TILE];
  __shared__ int swl[M_TILE];

  const int tid  = threadIdx.x;
  const int lane = tid & 63;
  const int wv   = tid >> 6;
  const int wu   = wv >> 1;     // unit-half  0..1
  const int wc2  = wv & 1;      // word-half  0..1
  const int quad = lane >> 4;
  const int colc = lane & 15;
  const int pb   = blockIdx.x;
  const int dir  = pb & 1;
  const int qb   = pb >> 1;
  const int tile = (qb & 1) ? (255 - (qb >> 1)) : (qb >> 1);

  // this block's c slice: [wu][rt 0..31][wc2][ci][lane] scalar fp32 (coalesced)
  float* cb = cws + (size_t)pb * (M_TILE * HID);

  if (tid < M_TILE) {
    int sw = sorted[tile * M_TILE + tid];
    swl[tid]  = sw;
    lenl[tid] = lengths[sw];
  }
  ((f32x4*)biasl)[tid] = ((const f32x4*)(biasg + dir * GATES))[tid];
  for (int i = tid; i < M_TILE * AROW / 2; i += 256) ((int*)A)[i] = 0;     // h=0 init
  for (int i = tid; i < M_TILE * HID / 4; i += 256)
    ((f32x4*)cb)[i] = (f32x4){0.f, 0.f, 0.f, 0.f};                         // c=0 init
  __syncthreads();

  { // char ids for the tile (via sorted ids)
    int w = tid >> 2, ch = tid & 3;
    ((i32x4*)charl)[tid] = ((const i32x4*)(char_ids + swl[w] * 16))[ch];
  }
  int Lmax = lenl[lane];
  for (int o = 32; o; o >>= 1) { int v = __shfl_xor(Lmax, o, 64); Lmax = Lmax > v ? Lmax : v; }
  __syncthreads();  // charl ready

  // stage x for timestep tt into A cols [256,320): wave wv covers words 16wv..16wv+15
  auto gather_x = [&](int tt) {
    int wl = wv * 16 + (lane >> 2);
    int part = lane & 3;
    int lw = lenl[wl];
    int pos = (dir == 0) ? tt : (lw - 1 - tt);
    pos = pos < 0 ? 0 : (pos > 15 ? 15 : pos);
    int cid = charl[wl * 16 + pos];
    const bf16x8* src = (const bf16x8*)(embw + cid * EMBD + part * 16);
    bf16x8 e0 = src[0], e1 = src[1];
    *(bf16x8*)(A + wl * AROW + HID + part * 16)     = e0;
    *(bf16x8*)(A + wl * AROW + HID + part * 16 + 8) = e1;
  };
  gather_x(0);

  // step-invariant lane constants (word dimension, per ci)
  int lenw[2], hadrb[2], oadr[2];
#pragma unroll
  for (int ci = 0; ci < 2; ++ci) {
    int wl = (wc2 * 2 + ci) * 16 + colc;
    lenw[ci]  = lenl[wl];
    hadrb[ci] = wl * AROW + 128 * wu + quad;                  // + 4*rt : bf16 h slot in A
    oadr[ci]  = swl[wl] * 512 + dir * 256 + 128 * wu + quad;  // + 4*rt : fp32 out slot
  }
  const short* wp = wsw + ((size_t)dir * 64 + wu * 32) * 10 * 64 * 8 + lane * 8;
  float* cwl = cb + (wu * 128 + wc2 * 2) * 64 + lane;   // + (rt*4 + ci)*64

  __syncthreads();  // x / zeros visible

#pragma unroll 1
  for (int t = 0; t < Lmax; ++t) {
    bf16x8 hx[2][10];  // B frags: lane = B[k = kk*32 + quad*8 + j][n = (2wc2+ci)*16 + colc]
#pragma unroll
    for (int ci = 0; ci < 2; ++ci)
#pragma unroll
      for (int kk = 0; kk < 10; ++kk)
        hx[ci][kk] = *(const bf16x8*)(A + ((wc2 * 2 + ci) * 16 + colc) * AROW + kk * 32 + quad * 8);

    __syncthreads();  // all waves snapshotted -> safe to overwrite h/x below

#pragma unroll 1
    for (int rt = 0; rt < 32; ++rt) {
      // c + bias loads issue first, ride under the weight loads
      float co[2];
#pragma unroll
      for (int ci = 0; ci < 2; ++ci) co[ci] = cwl[(rt * 4 + ci) * 64];  // coalesced
      f32x4 bias4 = *(const f32x4*)(biasl + 512 * wu + 16 * rt + 4 * quad);

      bf16x8 wc[10];  // this row-tile's weight A-fragments (single buffer)
#pragma unroll
      for (int kk = 0; kk < 10; ++kk) wc[kk] = *(const bf16x8*)(wp + (rt * 10 + kk) * 512);

      f32x4 acc[2];
      acc[0] = bias4;
      acc[1] = bias4;
#pragma unroll
      for (int kk = 0; kk < 10; ++kk)
#pragma unroll
        for (int ci = 0; ci < 2; ++ci)  // 2 independent acc chains
          acc[ci] = __builtin_amdgcn_mfma_f32_16x16x32_bf16(wc[kk], hx[ci][kk], acc[ci], 0, 0, 0);

#pragma unroll
      for (int ci = 0; ci < 2; ++ci) {
        // lane-private epilogue: regs = i,f,g,o of (unit 128wu+4rt+quad, word (2wc2+ci)*16+colc)
        float ig = fsig(acc[ci][0]);
        float fg = fsig(acc[ci][1]);
        float gg = ftanhf(acc[ci][2]);
        float og = fsig(acc[ci][3]);
        float co_v = co[ci];
        float c2 = fg * co_v + ig * gg;
        float h2 = og * ftanhf(c2);
        bool act = t < lenw[ci];
        cwl[(rt * 4 + ci) * 64] = act ? c2 : co_v;
        if (act) A[hadrb[ci] + 4 * rt] = tobf(h2);              // freeze h when masked
        if (t == lenw[ci] - 1) out[oadr[ci] + 4 * rt] = h2;     // final h in fp32
      }
    }

    gather_x(t + 1);   // x for next step (clamped; dead steps are masked)
    __syncthreads();   // h/x writes visible before next step's snapshots
  }
}

// ---------------- launch ----------------
extern "C" void kernel_launch(void* const* d_in, const int* in_sizes, int n_in,
                              void* d_out, int out_size, void* d_ws, size_t ws_size,
                              hipStream_t stream) {
  const int*   char_ids = (const int*)d_in[0];
  const int*   lengths  = (const int*)d_in[1];
  const float* emb      = (const float*)d_in[2];
  const float* Wihf     = (const float*)d_in[3];
  const float* Whhf     = (const float*)d_in[4];
  const float* bihf     = (const float*)d_in[5];
  const float* bhhf     = (const float*)d_in[6];
  const float* Wihb     = (const float*)d_in[7];
  const float* Whhb     = (const float*)d_in[8];
  const float* bihb     = (const float*)d_in[9];
  const float* bhhb     = (const float*)d_in[10];

  char* ws = (char*)d_ws;
  short* wsw   = (short*)(ws + OFF_WSW);
  short* embw  = (short*)(ws + OFF_EMB);
  float* biasg = (float*)(ws + OFF_BIAS);
  int*   sortd = (int*)(ws + OFF_SORT);
  int*   hist  = (int*)(ws + OFF_HIST);
  int*   basep = (int*)(ws + OFF_BASE);
  int*   cnt   = (int*)(ws + OFF_CNT);
  float* cws   = (float*)(ws + OFF_C);

  hipMemsetAsync(hist, 0, 192, stream);  // hist + base + cnt
  k_hist<<<64, 256, 0, stream>>>(lengths, hist);
  k_scan<<<1, 64, 0, stream>>>(hist, basep);
  k_scat<<<64, 256, 0, stream>>>(lengths, basep, cnt, sortd);
  prep_w<<<320, 256, 0, stream>>>(Wihf, Whhf, Wihb, Whhb, wsw);
  prep_misc<<<40, 256, 0, stream>>>(emb, bihf, bhhf, bihb, bhhb, embw, biasg);
  lstm_main<<<512, 256, 0, stream>>>(char_ids, lengths, wsw, embw, biasg, sortd,
                                     cws, (float*)d_out);
}

// Round 11
// 574.263 us; speedup vs baseline: 1.5914x; 1.5914x over previous
//
#include <hip/hip_runtime.h>

// ---------------- problem constants ----------------
#define N_WORDS 16384
#define MAXL    16
#define VOCABSZ 128
#define EMBD    64
#define HID     256
#define GATES   1024        // 4*HID
#define KTOT    320         // HID + EMBD (x folded into K)
#define AROW    328         // A row stride in shorts (656 B = 640 + 16 pad)
#define M_TILE  64          // words per workgroup
#define NT      256         // word tiles (N_WORDS / M_TILE)

typedef __attribute__((ext_vector_type(8))) short bf16x8;  // 8 bf16 = 4 VGPRs
typedef __attribute__((ext_vector_type(4))) float f32x4;
typedef __attribute__((ext_vector_type(4))) int   i32x4;

// ---------------- workspace layout (bytes) ----------------
// wsw : swizzled weights, A-fragment order: [dir][R 0..63][kk 0..9][lane 0..63][8 bf16]
//       row-tile R covers units 4R..4R+3, rows m = 4*uu + gate_type (unit-major interleave)
#define OFF_WSW   0ul          // 2*64*10*64*16 = 1310720
#define OFF_EMB   1310720ul    // 128*64 bf16 = 16384
#define OFF_BIAS  1327104ul    // 2*1024 f32 = 8192 (interleaved unit-major: [4*unit+type])
#define OFF_SORT  1335296ul    // 16384 ints = 65536
#define OFF_HIST  1400832ul    // 16 ints
#define OFF_BASE  1400896ul    // 16 ints
#define OFF_CNT   1400960ul    // 16 ints
#define OFF_C     1401088ul    // 512 blocks * 64 KB = 33554432  (coalesced fp32 cell state)

__device__ inline short tobf(float f) {           // fp32 -> bf16 RNE
  unsigned u = __float_as_uint(f);
  unsigned r = (u + 0x7fffu + ((u >> 16) & 1u)) >> 16;
  return (short)r;
}
// raw transcendental units via inline asm (assembles per cdna4_isa.md §3)
__device__ inline float aexp2(float x) { float r; asm("v_exp_f32 %0, %1" : "=v"(r) : "v"(x)); return r; }
__device__ inline float arcp(float x)  { float r; asm("v_rcp_f32 %0, %1" : "=v"(r) : "v"(x)); return r; }
__device__ inline float fsig(float x)   { return arcp(1.0f + aexp2(x * -1.4426950408889634f)); }
__device__ inline float ftanhf(float x) { return 1.0f - 2.0f * arcp(1.0f + aexp2(x * 2.8853900817779268f)); }

// ---------------- prep: weight swizzle into MFMA *A*-fragment layout ----------------
// A[m][k] for 16x16x32: m = lane&15, k = kk*32 + (lane>>4)*8 + j
// row m of row-tile R: unit = 4R + (m>>2), gate type = m&3, gate row g = type*256 + unit
__global__ void prep_w(const float* __restrict__ Wihf, const float* __restrict__ Whhf,
                       const float* __restrict__ Wihb, const float* __restrict__ Whhb,
                       short* __restrict__ wsw) {
  int id = blockIdx.x * 256 + threadIdx.x;       // 2*64*10*64 = 81920
  if (id >= 81920) return;
  int d    = id / 40960;
  int r    = id % 40960;
  int R    = r / 640;
  int r2   = r % 640;
  int kk   = r2 / 64;
  int lane = r2 % 64;
  int m    = lane & 15;
  int unit = R * 4 + (m >> 2);
  int ty   = m & 3;
  int g    = ty * 256 + unit;
  int kb   = kk * 32 + (lane >> 4) * 8;
  const float* Wih = d ? Wihb : Wihf;
  const float* Whh = d ? Whhb : Whhf;
  bf16x8 v;
#pragma unroll
  for (int j = 0; j < 8; ++j) {
    int k = kb + j;
    float f = (k < HID) ? Whh[g * HID + k] : Wih[g * EMBD + (k - HID)];
    v[j] = tobf(f);
  }
  ((bf16x8*)wsw)[id] = v;
}

// emb -> bf16, biases -> interleaved sum ([4*unit+type], matches C-row interleave)
__global__ void prep_misc(const float* __restrict__ emb,
                          const float* __restrict__ bihf, const float* __restrict__ bhhf,
                          const float* __restrict__ bihb, const float* __restrict__ bhhb,
                          short* __restrict__ embw, float* __restrict__ biasg) {
  int id = blockIdx.x * 256 + threadIdx.x;       // 8192 + 2048 = 10240
  if (id < VOCABSZ * EMBD) {
    embw[id] = tobf(emb[id]);
  } else {
    int r = id - VOCABSZ * EMBD;
    if (r < 2048) {
      int d = r >> 10, n = r & 1023;
      int g = (n & 3) * 256 + (n >> 2);
      biasg[r] = d ? (bihb[g] + bhhb[g]) : (bihf[g] + bhhf[g]);
    }
  }
}

// ---------------- length bucketing ----------------
__global__ void k_hist(const int* __restrict__ lengths, int* __restrict__ hist) {
  int id = blockIdx.x * 256 + threadIdx.x;
  if (id < N_WORDS) atomicAdd(&hist[lengths[id] - 1], 1);
}
__global__ void k_scan(const int* __restrict__ hist, int* __restrict__ basep) {
  if (threadIdx.x == 0 && blockIdx.x == 0) {
    int s = 0;
    for (int i = 0; i < 16; ++i) { basep[i] = s; s += hist[i]; }
  }
}
__global__ void k_scat(const int* __restrict__ lengths, const int* __restrict__ basep,
                       int* __restrict__ cnt, int* __restrict__ sorted) {
  int id = blockIdx.x * 256 + threadIdx.x;
  if (id < N_WORDS) {
    int b = lengths[id] - 1;
    int p = basep[b] + atomicAdd(&cnt[b], 1);
    sorted[p] = id;
  }
}

// ---------------- main fused BiLSTM kernel ----------------
// R11 = R10 wave split + R7 ping-pong + (256,2):
//   wave (wu, wc2): units [128wu,128wu+128) = rt [0..32) at base 32wu,
//                   words [32wc2, 32wc2+32) = ci {0,1}
// hx 80 regs + weight ping-pong 80 + acc 8 + misc ~45 ≈ 215 <= 256
// -> 2 blocks/CU (R9-verified at this budget) AND full prefetch latency hiding
// -> wc2-wave pairs stream identical weight addresses -> L1 dedup (R10-verified:
//    FETCH did not double) -> effective single weight stream per block.
// Race safety: hx snapshot (all waves) -> barrier -> disjoint h/c/out writes ->
// gather_x (x region disjoint) -> barrier.  2 barriers/t.
__global__ __launch_bounds__(256, 2) void lstm_main(
    const int* __restrict__ char_ids, const int* __restrict__ lengths,
    const short* __restrict__ wsw, const short* __restrict__ embw,
    const float* __restrict__ biasg, const int* __restrict__ sorted,
    float* __restrict__ cws, float* __restrict__ out) {
  __shared__ __align__(16) short A[M_TILE * AROW];   // [word][ h(256) | x(64) | pad(8) ] bf16
  __shared__ __align__(16) int   charl[M_TILE * 16];
  __shared__ __align__(16) float biasl[GATES];
  __shared__ int lenl[M_TILE];
  __shared__ int swl[M_TILE];

  const int tid  = threadIdx.x;
  const int lane = tid & 63;
  const int wv   = tid >> 6;
  const int wu   = wv >> 1;     // unit-half  0..1
  const int wc2  = wv & 1;      // word-half  0..1
  const int quad = lane >> 4;
  const int colc = lane & 15;
  const int pb   = blockIdx.x;
  const int dir  = pb & 1;
  const int qb   = pb >> 1;
  const int tile = (qb & 1) ? (255 - (qb >> 1)) : (qb >> 1);

  // this block's c slice: [wu][rt 0..31][wc2*2+ci][lane] scalar fp32 (coalesced)
  float* cb = cws + (size_t)pb * (M_TILE * HID);

  if (tid < M_TILE) {
    int sw = sorted[tile * M_TILE + tid];
    swl[tid]  = sw;
    lenl[tid] = lengths[sw];
  }
  ((f32x4*)biasl)[tid] = ((const f32x4*)(biasg + dir * GATES))[tid];
  for (int i = tid; i < M_TILE * AROW / 2; i += 256) ((int*)A)[i] = 0;     // h=0 init
  for (int i = tid; i < M_TILE * HID / 4; i += 256)
    ((f32x4*)cb)[i] = (f32x4){0.f, 0.f, 0.f, 0.f};                         // c=0 init
  __syncthreads();

  { // char ids for the tile (via sorted ids)
    int w = tid >> 2, ch = tid & 3;
    ((i32x4*)charl)[tid] = ((const i32x4*)(char_ids + swl[w] * 16))[ch];
  }
  int Lmax = lenl[lane];
  for (int o = 32; o; o >>= 1) { int v = __shfl_xor(Lmax, o, 64); Lmax = Lmax > v ? Lmax : v; }
  __syncthreads();  // charl ready

  // stage x for timestep tt into A cols [256,320): wave wv covers words 16wv..16wv+15
  auto gather_x = [&](int tt) {
    int wl = wv * 16 + (lane >> 2);
    int part = lane & 3;
    int lw = lenl[wl];
    int pos = (dir == 0) ? tt : (lw - 1 - tt);
    pos = pos < 0 ? 0 : (pos > 15 ? 15 : pos);
    int cid = charl[wl * 16 + pos];
    const bf16x8* src = (const bf16x8*)(embw + cid * EMBD + part * 16);
    bf16x8 e0 = src[0], e1 = src[1];
    *(bf16x8*)(A + wl * AROW + HID + part * 16)     = e0;
    *(bf16x8*)(A + wl * AROW + HID + part * 16 + 8) = e1;
  };
  gather_x(0);

  // step-invariant lane constants (word dimension, per ci)
  int lenw[2], hadrb[2], oadr[2];
#pragma unroll
  for (int ci = 0; ci < 2; ++ci) {
    int wl = (wc2 * 2 + ci) * 16 + colc;
    lenw[ci]  = lenl[wl];
    hadrb[ci] = wl * AROW + 128 * wu + quad;                  // + 4*rt : bf16 h slot in A
    oadr[ci]  = swl[wl] * 512 + dir * 256 + 128 * wu + quad;  // + 4*rt : fp32 out slot
  }
  const short* wp = wsw + ((size_t)dir * 64 + wu * 32) * 10 * 64 * 8 + lane * 8;
  float* cwl = cb + (wu * 128 + wc2 * 2) * 64 + lane;   // + (rt*4 + ci)*64

  __syncthreads();  // x / zeros visible

#pragma unroll 1
  for (int t = 0; t < Lmax; ++t) {
    bf16x8 hx[2][10];  // B frags: lane = B[k = kk*32 + quad*8 + j][n = (2wc2+ci)*16 + colc]
#pragma unroll
    for (int ci = 0; ci < 2; ++ci)
#pragma unroll
      for (int kk = 0; kk < 10; ++kk)
        hx[ci][kk] = *(const bf16x8*)(A + ((wc2 * 2 + ci) * 16 + colc) * AROW + kk * 32 + quad * 8);

    __syncthreads();  // all waves snapshotted -> safe to overwrite h/x below

    bf16x8 wA[10], wB[10];
#pragma unroll
    for (int kk = 0; kk < 10; ++kk) wA[kk] = *(const bf16x8*)(wp + kk * 512);

    auto wtile = [&](int rt, bf16x8(&wc)[10], bf16x8(&wn)[10], int pre) {
      // c + bias loads issue first, ride under the weight prefetch
      float co[2];
#pragma unroll
      for (int ci = 0; ci < 2; ++ci) co[ci] = cwl[(rt * 4 + ci) * 64];  // coalesced
      f32x4 bias4 = *(const f32x4*)(biasl + 512 * wu + 16 * rt + 4 * quad);
      if (pre >= 0) {  // prefetch next row-tile's weights (vmcnt stays > 0 over MFMAs)
#pragma unroll
        for (int kk = 0; kk < 10; ++kk) wn[kk] = *(const bf16x8*)(wp + (pre * 10 + kk) * 512);
      }
      f32x4 acc[2];
      acc[0] = bias4;
      acc[1] = bias4;
#pragma unroll
      for (int kk = 0; kk < 10; ++kk)
#pragma unroll
        for (int ci = 0; ci < 2; ++ci)  // 2 independent acc chains
          acc[ci] = __builtin_amdgcn_mfma_f32_16x16x32_bf16(wc[kk], hx[ci][kk], acc[ci], 0, 0, 0);

#pragma unroll
      for (int ci = 0; ci < 2; ++ci) {
        // lane-private epilogue: regs = i,f,g,o of (unit 128wu+4rt+quad, word (2wc2+ci)*16+colc)
        float ig = fsig(acc[ci][0]);
        float fg = fsig(acc[ci][1]);
        float gg = ftanhf(acc[ci][2]);
        float og = fsig(acc[ci][3]);
        float co_v = co[ci];
        float c2 = fg * co_v + ig * gg;
        float h2 = og * ftanhf(c2);
        bool act = t < lenw[ci];
        if (act) {
          cwl[(rt * 4 + ci) * 64] = c2;                         // store only live words
          A[hadrb[ci] + 4 * rt] = tobf(h2);                     // freeze h when masked
        }
        if (t == lenw[ci] - 1) out[oadr[ci] + 4 * rt] = h2;     // final h in fp32
      }
    };

#pragma unroll 1
    for (int rt2 = 0; rt2 < 32; rt2 += 2) {   // ping-pong weight buffers, static indices
      wtile(rt2,     wA, wB, rt2 + 1);
      wtile(rt2 + 1, wB, wA, (rt2 + 2 < 32) ? (rt2 + 2) : -1);
    }

    gather_x(t + 1);   // x for next step (clamped; dead steps are masked)
    __syncthreads();   // h/x writes visible before next step's snapshots
  }
}

// ---------------- launch ----------------
extern "C" void kernel_launch(void* const* d_in, const int* in_sizes, int n_in,
                              void* d_out, int out_size, void* d_ws, size_t ws_size,
                              hipStream_t stream) {
  const int*   char_ids = (const int*)d_in[0];
  const int*   lengths  = (const int*)d_in[1];
  const float* emb      = (const float*)d_in[2];
  const float* Wihf     = (const float*)d_in[3];
  const float* Whhf     = (const float*)d_in[4];
  const float* bihf     = (const float*)d_in[5];
  const float* bhhf     = (const float*)d_in[6];
  const float* Wihb     = (const float*)d_in[7];
  const float* Whhb     = (const float*)d_in[8];
  const float* bihb     = (const float*)d_in[9];
  const float* bhhb     = (const float*)d_in[10];

  char* ws = (char*)d_ws;
  short* wsw   = (short*)(ws + OFF_WSW);
  short* embw  = (short*)(ws + OFF_EMB);
  float* biasg = (float*)(ws + OFF_BIAS);
  int*   sortd = (int*)(ws + OFF_SORT);
  int*   hist  = (int*)(ws + OFF_HIST);
  int*   basep = (int*)(ws + OFF_BASE);
  int*   cnt   = (int*)(ws + OFF_CNT);
  float* cws   = (float*)(ws + OFF_C);

  hipMemsetAsync(hist, 0, 192, stream);  // hist + base + cnt
  k_hist<<<64, 256, 0, stream>>>(lengths, hist);
  k_scan<<<1, 64, 0, stream>>>(hist, basep);
  k_scat<<<64, 256, 0, stream>>>(lengths, basep, cnt, sortd);
  prep_w<<<320, 256, 0, stream>>>(Wihf, Whhf, Wihb, Whhb, wsw);
  prep_misc<<<40, 256, 0, stream>>>(emb, bihf, bhhf, bihb, bhhb, embw, biasg);
  lstm_main<<<512, 256, 0, stream>>>(char_ids, lengths, wsw, embw, biasg, sortd,
                                     cws, (float*)d_out);
}